// Round 1
// baseline (1077.846 us; speedup 1.0000x reference)
//
#include <hip/hip_runtime.h>
#include <cstddef>

// ---------------------------------------------------------------------------
// Decagon fused pipeline, fp32 baseline.
//   h1 = relu(dF @ W1 + b1)                      (1000 x 2048)@(2048 x 128)
//   xF[0:1000] = relu(h1 @ W2 + b2); xF[1000:] = proteinEmb
//   agg/cnt = segment_sum over edges with dst < 1000 (only rows we consume)
//   finalX = relu(mean @ sageWl + sageBl + xF @ sageWr)  rows 0..999 only
//   out[t, j] = hardshrink(hardshrink(xd @ outW1 + outB1) @ outW2s + outB2s)
//     with xd = [finalX[tpl[t,0]], finalX[tpl[t,1]]], W2s = outW2[:, sampleSes]
// ---------------------------------------------------------------------------

__device__ __forceinline__ float hshrink(float v) {
    return (fabsf(v) > 1e-6f) ? v : 0.0f;
}

// C = relu(A @ W + bias), A:(M,K), W:(K,128), C:(M,128). 8 rows/block.
__global__ __launch_bounds__(256) void k_mlp(const float* __restrict__ A,
                                             const float* __restrict__ W,
                                             const float* __restrict__ bias,
                                             float* __restrict__ C, int M, int K) {
    __shared__ float As[8 * 128];
    const int tid = threadIdx.x;
    const int r0  = blockIdx.x * 8;
    const int col = tid & 127;
    const int rh  = tid >> 7;   // 0/1 -> rows rh*4 .. rh*4+3
    float acc[4] = {0.f, 0.f, 0.f, 0.f};

    const int sr  = tid >> 5;        // staging row 0..7
    const int sc4 = (tid & 31) * 4;  // staging col (float4)
    const int ra  = min(r0 + sr, M - 1);

    for (int kc = 0; kc < K; kc += 128) {
        __syncthreads();
        float4 v = *(const float4*)(A + (size_t)ra * K + kc + sc4);
        *(float4*)&As[sr * 128 + sc4] = v;
        __syncthreads();
        for (int k = 0; k < 128; k += 4) {
            float w0 = W[(size_t)(kc + k + 0) * 128 + col];
            float w1 = W[(size_t)(kc + k + 1) * 128 + col];
            float w2 = W[(size_t)(kc + k + 2) * 128 + col];
            float w3 = W[(size_t)(kc + k + 3) * 128 + col];
#pragma unroll
            for (int r = 0; r < 4; r++) {
                float4 av = *(const float4*)&As[(rh * 4 + r) * 128 + k];
                acc[r] = fmaf(av.x, w0, acc[r]);
                acc[r] = fmaf(av.y, w1, acc[r]);
                acc[r] = fmaf(av.z, w2, acc[r]);
                acc[r] = fmaf(av.w, w3, acc[r]);
            }
        }
    }
    float bb = bias[col];
#pragma unroll
    for (int r = 0; r < 4; r++) {
        int row = r0 + rh * 4 + r;
        if (row < M) C[(size_t)row * 128 + col] = fmaxf(acc[r] + bb, 0.f);
    }
}

// Edge scatter: agg[dst] += xF[src], cnt[dst] += 1, only dst < nD.
// 4 threads per edge, 32 floats each.
__global__ __launch_bounds__(256) void k_edge(const int* __restrict__ ei,
                                              const float* __restrict__ xF,
                                              float* __restrict__ agg,
                                              float* __restrict__ cnt, int E, int nD) {
    int g = blockIdx.x * 256 + threadIdx.x;
    int e = g >> 2, j = g & 3;
    if (e >= E) return;
    int dst = ei[E + e];
    if (dst >= nD) return;
    int src = ei[e];
    if (j == 0) atomicAdd(cnt + dst, 1.0f);
    const float4* xs = (const float4*)(xF + (size_t)src * 128) + j * 8;
    float* ad = agg + (size_t)dst * 128 + j * 32;
#pragma unroll
    for (int i = 0; i < 8; i++) {
        float4 v = xs[i];
        atomicAdd(ad + i * 4 + 0, v.x);
        atomicAdd(ad + i * 4 + 1, v.y);
        atomicAdd(ad + i * 4 + 2, v.z);
        atomicAdd(ad + i * 4 + 3, v.w);
    }
}

// finalX = relu((agg/max(cnt,1)) @ Wl + bl + xF @ Wr), rows 0..M-1. 8 rows/block.
__global__ __launch_bounds__(256) void k_sage(const float* __restrict__ agg,
                                              const float* __restrict__ cnt,
                                              const float* __restrict__ xF,
                                              const float* __restrict__ Wl,
                                              const float* __restrict__ bl,
                                              const float* __restrict__ Wr,
                                              float* __restrict__ fX, int M) {
    __shared__ float ms[8 * 128];
    __shared__ float xs[8 * 128];
    const int tid = threadIdx.x;
    const int r0  = blockIdx.x * 8;
    const int col = tid & 127;
    const int rh  = tid >> 7;

    const int sr  = tid >> 5;
    const int sc4 = (tid & 31) * 4;
    const int ra  = min(r0 + sr, M - 1);
    float inv = 1.0f / fmaxf(cnt[ra], 1.0f);
    float4 av = *(const float4*)(agg + (size_t)ra * 128 + sc4);
    av.x *= inv; av.y *= inv; av.z *= inv; av.w *= inv;
    *(float4*)&ms[sr * 128 + sc4] = av;
    *(float4*)&xs[sr * 128 + sc4] = *(const float4*)(xF + (size_t)ra * 128 + sc4);
    __syncthreads();

    float acc[4] = {0.f, 0.f, 0.f, 0.f};
    for (int k = 0; k < 128; k += 4) {
#pragma unroll
        for (int u = 0; u < 4; u++) {
            float wl = Wl[(size_t)(k + u) * 128 + col];
            float wr = Wr[(size_t)(k + u) * 128 + col];
#pragma unroll
            for (int r = 0; r < 4; r++) {
                acc[r] = fmaf(ms[(rh * 4 + r) * 128 + k + u], wl, acc[r]);
                acc[r] = fmaf(xs[(rh * 4 + r) * 128 + k + u], wr, acc[r]);
            }
        }
    }
    float bb = bl[col];
#pragma unroll
    for (int r = 0; r < 4; r++) {
        int row = r0 + rh * 4 + r;
        if (row < M) fX[(size_t)row * 128 + col] = fmaxf(acc[r] + bb, 0.f);
    }
}

// Gather outW2[:, sampleSes] into padded (128 x 512) + outB2[sampleSes] into 512.
__global__ __launch_bounds__(256) void k_w2g(const float* __restrict__ oW2,
                                             const float* __restrict__ oB2,
                                             const int* __restrict__ sSes,
                                             float* __restrict__ W2p,
                                             float* __restrict__ B2p, int nSe, int S) {
    int t = blockIdx.x * 256 + threadIdx.x;
    if (t < 128 * 512) {
        int k = t >> 9, j = t & 511;
        W2p[t] = (j < S) ? oW2[(size_t)k * nSe + sSes[j]] : 0.f;
    } else {
        int j = t - 128 * 512;
        if (j < 512) B2p[j] = (j < S) ? oB2[sSes[j]] : 0.f;
    }
}

// Fused output: per block 32 tpl rows.
//   xd (32x256, gathered, LDS transposed) @ outW1 (256x128) -> o1 (32x128, LDS)
//   o1 @ W2p (128x512 padded) -> out (32xS)
__global__ __launch_bounds__(256) void k_out(const int* __restrict__ tpl,
                                             const float* __restrict__ fX,
                                             const float* __restrict__ W1,
                                             const float* __restrict__ B1,
                                             const float* __restrict__ W2,
                                             const float* __restrict__ B2,
                                             float* __restrict__ out, int T, int S) {
    __shared__ float smem[16384];          // 64 KB total
    float* xdT = smem;                     // [256][32] (phase 1), later o1 [32][132]
    float* wb  = smem + 8192;              // [64][128] weight staging (both phases)
    float* o1  = smem;                     // overlays xdT after phase 1
    int* ia = (int*)(smem + 8192);         // clobbered by first wb staging (ok)
    int* ib = ia + 32;

    const int tid = threadIdx.x;
    const int t0  = blockIdx.x * 32;

    if (tid < 32) {
        int t = min(t0 + tid, T - 1);
        ia[tid] = tpl[2 * t];
        ib[tid] = tpl[2 * t + 1];
    }
    __syncthreads();

    // stage xd transposed: xdT[k][row], k in [0,256)
    {
        const int row = tid & 31;
        const int pb  = tid >> 5;  // 0..7
#pragma unroll
        for (int i = 0; i < 8; i++) {
            int p = pb + i * 8;  // 0..63
            int drug = (p < 32) ? ia[row] : ib[row];
            float4 v = *(const float4*)(fX + (size_t)drug * 128 + (p & 31) * 4);
            int k0 = p * 4;
            xdT[(k0 + 0) * 32 + row] = v.x;
            xdT[(k0 + 1) * 32 + row] = v.y;
            xdT[(k0 + 2) * 32 + row] = v.z;
            xdT[(k0 + 3) * 32 + row] = v.w;
        }
    }

    const int cg = tid & 31;  // 4 cols each
    const int rg = tid >> 5;  // 4 rows each

    // ---- phase 1: o1 = hardshrink(xd @ W1 + B1) ----
    float acc[4][4] = {};
    for (int kc = 0; kc < 256; kc += 64) {
        __syncthreads();
#pragma unroll
        for (int i = 0; i < 8; i++) {
            int f4 = tid + i * 256;
            int kk = f4 >> 5, c4 = (f4 & 31) * 4;
            *(float4*)&wb[kk * 128 + c4] =
                *(const float4*)(W1 + (size_t)(kc + kk) * 128 + c4);
        }
        __syncthreads();
#pragma unroll 4
        for (int kk = 0; kk < 64; kk++) {
            float4 xv = *(const float4*)&xdT[(kc + kk) * 32 + rg * 4];
            float4 wv = *(const float4*)&wb[kk * 128 + cg * 4];
            acc[0][0] = fmaf(xv.x, wv.x, acc[0][0]);
            acc[0][1] = fmaf(xv.x, wv.y, acc[0][1]);
            acc[0][2] = fmaf(xv.x, wv.z, acc[0][2]);
            acc[0][3] = fmaf(xv.x, wv.w, acc[0][3]);
            acc[1][0] = fmaf(xv.y, wv.x, acc[1][0]);
            acc[1][1] = fmaf(xv.y, wv.y, acc[1][1]);
            acc[1][2] = fmaf(xv.y, wv.z, acc[1][2]);
            acc[1][3] = fmaf(xv.y, wv.w, acc[1][3]);
            acc[2][0] = fmaf(xv.z, wv.x, acc[2][0]);
            acc[2][1] = fmaf(xv.z, wv.y, acc[2][1]);
            acc[2][2] = fmaf(xv.z, wv.z, acc[2][2]);
            acc[2][3] = fmaf(xv.z, wv.w, acc[2][3]);
            acc[3][0] = fmaf(xv.w, wv.x, acc[3][0]);
            acc[3][1] = fmaf(xv.w, wv.y, acc[3][1]);
            acc[3][2] = fmaf(xv.w, wv.z, acc[3][2]);
            acc[3][3] = fmaf(xv.w, wv.w, acc[3][3]);
        }
    }
    __syncthreads();  // all xdT reads done before o1 overlay write
    {
        float4 b1v = *(const float4*)(B1 + cg * 4);
        float bb[4] = {b1v.x, b1v.y, b1v.z, b1v.w};
#pragma unroll
        for (int r = 0; r < 4; r++) {
            float4 o;
            o.x = hshrink(acc[r][0] + bb[0]);
            o.y = hshrink(acc[r][1] + bb[1]);
            o.z = hshrink(acc[r][2] + bb[2]);
            o.w = hshrink(acc[r][3] + bb[3]);
            *(float4*)&o1[(rg * 4 + r) * 132 + cg * 4] = o;
        }
    }
    // visibility of o1 covered by first __syncthreads below

    // ---- phase 2: out = hardshrink(o1 @ W2p + B2p), 4 column blocks of 128 ----
    for (int cc = 0; cc < 4; cc++) {
        int c0 = cc * 128 + cg * 4;
        float acc2[4][4] = {};
        for (int kc = 0; kc < 128; kc += 64) {
            __syncthreads();
#pragma unroll
            for (int i = 0; i < 8; i++) {
                int f4 = tid + i * 256;
                int kk = f4 >> 5, j4 = (f4 & 31) * 4;
                *(float4*)&wb[kk * 128 + j4] =
                    *(const float4*)(W2 + (size_t)(kc + kk) * 512 + cc * 128 + j4);
            }
            __syncthreads();
            for (int kk = 0; kk < 64; kk += 4) {
                float4 a0 = *(const float4*)&o1[(rg * 4 + 0) * 132 + kc + kk];
                float4 a1 = *(const float4*)&o1[(rg * 4 + 1) * 132 + kc + kk];
                float4 a2 = *(const float4*)&o1[(rg * 4 + 2) * 132 + kc + kk];
                float4 a3 = *(const float4*)&o1[(rg * 4 + 3) * 132 + kc + kk];
                const float* pa0 = &a0.x;
                const float* pa1 = &a1.x;
                const float* pa2 = &a2.x;
                const float* pa3 = &a3.x;
#pragma unroll
                for (int u = 0; u < 4; u++) {
                    float4 wv = *(const float4*)&wb[(kk + u) * 128 + cg * 4];
                    float v0 = pa0[u], v1 = pa1[u], v2 = pa2[u], v3 = pa3[u];
                    acc2[0][0] = fmaf(v0, wv.x, acc2[0][0]);
                    acc2[0][1] = fmaf(v0, wv.y, acc2[0][1]);
                    acc2[0][2] = fmaf(v0, wv.z, acc2[0][2]);
                    acc2[0][3] = fmaf(v0, wv.w, acc2[0][3]);
                    acc2[1][0] = fmaf(v1, wv.x, acc2[1][0]);
                    acc2[1][1] = fmaf(v1, wv.y, acc2[1][1]);
                    acc2[1][2] = fmaf(v1, wv.z, acc2[1][2]);
                    acc2[1][3] = fmaf(v1, wv.w, acc2[1][3]);
                    acc2[2][0] = fmaf(v2, wv.x, acc2[2][0]);
                    acc2[2][1] = fmaf(v2, wv.y, acc2[2][1]);
                    acc2[2][2] = fmaf(v2, wv.z, acc2[2][2]);
                    acc2[2][3] = fmaf(v2, wv.w, acc2[2][3]);
                    acc2[3][0] = fmaf(v3, wv.x, acc2[3][0]);
                    acc2[3][1] = fmaf(v3, wv.y, acc2[3][1]);
                    acc2[3][2] = fmaf(v3, wv.z, acc2[3][2]);
                    acc2[3][3] = fmaf(v3, wv.w, acc2[3][3]);
                }
            }
        }
        if (c0 + 3 < S) {
            float4 b2v = *(const float4*)(B2 + c0);
#pragma unroll
            for (int r = 0; r < 4; r++) {
                int t = t0 + rg * 4 + r;
                if (t < T) {
                    float4 o;
                    o.x = hshrink(acc2[r][0] + b2v.x);
                    o.y = hshrink(acc2[r][1] + b2v.y);
                    o.z = hshrink(acc2[r][2] + b2v.z);
                    o.w = hshrink(acc2[r][3] + b2v.w);
                    *(float4*)(out + (size_t)t * S + c0) = o;
                }
            }
        }
    }
}

extern "C" void kernel_launch(void* const* d_in, const int* in_sizes, int n_in,
                              void* d_out, int out_size, void* d_ws, size_t ws_size,
                              hipStream_t stream) {
    const float* dF   = (const float*)d_in[0];
    const int*   ei   = (const int*)d_in[1];
    const int*   tpl  = (const int*)d_in[2];
    const int*   sSes = (const int*)d_in[3];
    const float* W1   = (const float*)d_in[4];
    const float* b1   = (const float*)d_in[5];
    const float* W2   = (const float*)d_in[6];
    const float* b2   = (const float*)d_in[7];
    const float* pE   = (const float*)d_in[8];
    const float* sWl  = (const float*)d_in[9];
    const float* sBl  = (const float*)d_in[10];
    const float* sWr  = (const float*)d_in[11];
    const float* oW1  = (const float*)d_in[12];
    const float* oB1  = (const float*)d_in[13];
    const float* oW2  = (const float*)d_in[14];
    const float* oB2  = (const float*)d_in[15];

    const int D    = 128;
    const int F    = in_sizes[4] / D;   // 2048
    const int nD   = in_sizes[0] / F;   // 1000
    const int E    = in_sizes[1] / 2;   // 640000
    const int T    = in_sizes[2] / 2;   // 150000
    const int S    = in_sizes[3];       // 500 (assumed %4==0)
    const int nPro = in_sizes[8] / D;   // 20000
    const int nSe  = in_sizes[15];      // 964

    float* ws  = (float*)d_ws;
    float* xF  = ws;                                // (nD+nPro)*128
    float* h1  = xF + (size_t)(nD + nPro) * D;      // nD*128
    float* agg = h1 + (size_t)nD * D;               // nD*128
    float* cnt = agg + (size_t)nD * D;              // nD (padded to 1024)
    float* fX  = cnt + 1024;                        // nD*128
    float* W2p = fX + (size_t)nD * D;               // 128*512
    float* B2p = W2p + 128 * 512;                   // 512

    // MLP: h1 = relu(dF@W1+b1); xF[:nD] = relu(h1@W2+b2)
    k_mlp<<<(nD + 7) / 8, 256, 0, stream>>>(dF, W1, b1, h1, nD, F);
    k_mlp<<<(nD + 7) / 8, 256, 0, stream>>>(h1, W2, b2, xF, nD, D);
    // xF[nD:] = proteinEmb
    hipMemcpyAsync(xF + (size_t)nD * D, pE, (size_t)nPro * D * sizeof(float),
                   hipMemcpyDeviceToDevice, stream);
    // zero agg + cnt
    hipMemsetAsync(agg, 0, ((size_t)nD * D + 1024) * sizeof(float), stream);
    // edge scatter (only dst < nD matters downstream)
    k_edge<<<(E * 4 + 255) / 256, 256, 0, stream>>>(ei, xF, agg, cnt, E, nD);
    // SAGE rows 0..nD-1
    k_sage<<<(nD + 7) / 8, 256, 0, stream>>>(agg, cnt, xF, sWl, sBl, sWr, fX, nD);
    // gather sampled outW2 columns (padded to 512)
    k_w2g<<<(128 * 512 + 512 + 255) / 256, 256, 0, stream>>>(oW2, oB2, sSes, W2p, B2p,
                                                             nSe, S);
    // fused final layers
    k_out<<<(T + 31) / 32, 256, 0, stream>>>(tpl, fX, oW1, oB1, W2p, B2p,
                                             (float*)d_out, T, S);
}

// Round 2
// 770.128 us; speedup vs baseline: 1.3996x; 1.3996x over previous
//
#include <hip/hip_runtime.h>
#include <cstddef>

// ---------------------------------------------------------------------------
// Decagon pipeline, fp32, algebraically collapsed output layers.
// Key identity: hardshrink(v, 1e-6) == v to within 1e-6, so
//   out2[t] = hshrink( xd[t] @ oW1 @ W2s + oB1 @ W2s + oB2s )
//           = hshrink( PP[a] + QQ[b] + Cvec )
// with PP/QQ precomputed over the 1000 drugs (not the 150k pairs).
// Dropping the inner hardshrink perturbs out2 by <= 1e-6 * sum|W2 col| ~ 5e-6,
// far below the 5.2e-3 absmax threshold (ref magnitude ~0.26).
// ---------------------------------------------------------------------------

__device__ __forceinline__ float hshrink(float v) {
    return (fabsf(v) > 1e-6f) ? v : 0.0f;
}

// C = relu(A @ W + bias), A:(M,K), W:(K,128), C:(M,128). 8 rows/block.
__global__ __launch_bounds__(256) void k_mlp(const float* __restrict__ A,
                                             const float* __restrict__ W,
                                             const float* __restrict__ bias,
                                             float* __restrict__ C, int M, int K) {
    __shared__ float As[8 * 128];
    const int tid = threadIdx.x;
    const int r0  = blockIdx.x * 8;
    const int col = tid & 127;
    const int rh  = tid >> 7;   // 0/1 -> rows rh*4 .. rh*4+3
    float acc[4] = {0.f, 0.f, 0.f, 0.f};

    const int sr  = tid >> 5;        // staging row 0..7
    const int sc4 = (tid & 31) * 4;  // staging col (float4)
    const int ra  = min(r0 + sr, M - 1);

    for (int kc = 0; kc < K; kc += 128) {
        __syncthreads();
        float4 v = *(const float4*)(A + (size_t)ra * K + kc + sc4);
        *(float4*)&As[sr * 128 + sc4] = v;
        __syncthreads();
        for (int k = 0; k < 128; k += 4) {
            float w0 = W[(size_t)(kc + k + 0) * 128 + col];
            float w1 = W[(size_t)(kc + k + 1) * 128 + col];
            float w2 = W[(size_t)(kc + k + 2) * 128 + col];
            float w3 = W[(size_t)(kc + k + 3) * 128 + col];
#pragma unroll
            for (int r = 0; r < 4; r++) {
                float4 av = *(const float4*)&As[(rh * 4 + r) * 128 + k];
                acc[r] = fmaf(av.x, w0, acc[r]);
                acc[r] = fmaf(av.y, w1, acc[r]);
                acc[r] = fmaf(av.z, w2, acc[r]);
                acc[r] = fmaf(av.w, w3, acc[r]);
            }
        }
    }
    float bb = bias[col];
#pragma unroll
    for (int r = 0; r < 4; r++) {
        int row = r0 + rh * 4 + r;
        if (row < M) C[(size_t)row * 128 + col] = fmaxf(acc[r] + bb, 0.f);
    }
}

// Edge scatter: agg[dst] += xF[src], cnt[dst] += 1, only dst < nD.
__global__ __launch_bounds__(256) void k_edge(const int* __restrict__ ei,
                                              const float* __restrict__ xF,
                                              float* __restrict__ agg,
                                              float* __restrict__ cnt, int E, int nD) {
    int g = blockIdx.x * 256 + threadIdx.x;
    int e = g >> 2, j = g & 3;
    if (e >= E) return;
    int dst = ei[E + e];
    if (dst >= nD) return;
    int src = ei[e];
    if (j == 0) atomicAdd(cnt + dst, 1.0f);
    const float4* xs = (const float4*)(xF + (size_t)src * 128) + j * 8;
    float* ad = agg + (size_t)dst * 128 + j * 32;
#pragma unroll
    for (int i = 0; i < 8; i++) {
        float4 v = xs[i];
        atomicAdd(ad + i * 4 + 0, v.x);
        atomicAdd(ad + i * 4 + 1, v.y);
        atomicAdd(ad + i * 4 + 2, v.z);
        atomicAdd(ad + i * 4 + 3, v.w);
    }
}

// finalX = relu((agg/max(cnt,1)) @ Wl + bl + xF @ Wr), rows 0..M-1. 8 rows/block.
__global__ __launch_bounds__(256) void k_sage(const float* __restrict__ agg,
                                              const float* __restrict__ cnt,
                                              const float* __restrict__ xF,
                                              const float* __restrict__ Wl,
                                              const float* __restrict__ bl,
                                              const float* __restrict__ Wr,
                                              float* __restrict__ fX, int M) {
    __shared__ float ms[8 * 128];
    __shared__ float xs[8 * 128];
    const int tid = threadIdx.x;
    const int r0  = blockIdx.x * 8;
    const int col = tid & 127;
    const int rh  = tid >> 7;

    const int sr  = tid >> 5;
    const int sc4 = (tid & 31) * 4;
    const int ra  = min(r0 + sr, M - 1);
    float inv = 1.0f / fmaxf(cnt[ra], 1.0f);
    float4 av = *(const float4*)(agg + (size_t)ra * 128 + sc4);
    av.x *= inv; av.y *= inv; av.z *= inv; av.w *= inv;
    *(float4*)&ms[sr * 128 + sc4] = av;
    *(float4*)&xs[sr * 128 + sc4] = *(const float4*)(xF + (size_t)ra * 128 + sc4);
    __syncthreads();

    float acc[4] = {0.f, 0.f, 0.f, 0.f};
    for (int k = 0; k < 128; k += 4) {
#pragma unroll
        for (int u = 0; u < 4; u++) {
            float wl = Wl[(size_t)(k + u) * 128 + col];
            float wr = Wr[(size_t)(k + u) * 128 + col];
#pragma unroll
            for (int r = 0; r < 4; r++) {
                acc[r] = fmaf(ms[(rh * 4 + r) * 128 + k + u], wl, acc[r]);
                acc[r] = fmaf(xs[(rh * 4 + r) * 128 + k + u], wr, acc[r]);
            }
        }
    }
    float bb = bl[col];
#pragma unroll
    for (int r = 0; r < 4; r++) {
        int row = r0 + rh * 4 + r;
        if (row < M) fX[(size_t)row * 128 + col] = fmaxf(acc[r] + bb, 0.f);
    }
}

// Gather outW2[:, sampleSes] into padded (128 x 512) + outB2[sampleSes] into 512.
__global__ __launch_bounds__(256) void k_w2g(const float* __restrict__ oW2,
                                             const float* __restrict__ oB2,
                                             const int* __restrict__ sSes,
                                             float* __restrict__ W2p,
                                             float* __restrict__ B2p, int nSe, int S) {
    int t = blockIdx.x * 256 + threadIdx.x;
    if (t < 128 * 512) {
        int k = t >> 9, j = t & 511;
        W2p[t] = (j < S) ? oW2[(size_t)k * nSe + sSes[j]] : 0.f;
    } else {
        int j = t - 128 * 512;
        if (j < 512) B2p[j] = (j < S) ? oB2[sSes[j]] : 0.f;
    }
}

// Generic small GEMM: C(M x 512) = A(M x 128) @ B(128 x 512), no activation.
// Block tile 16 rows x 128 cols; grid = (ceil(M/16), 4). ldb/ldc parametric.
__global__ __launch_bounds__(256) void k_g16(const float* __restrict__ A,
                                             const float* __restrict__ B,
                                             float* __restrict__ C, int M,
                                             int ldb, int ldc) {
    __shared__ float As[16 * 128];
    const int tid = threadIdx.x;
    const int r0  = blockIdx.x * 16;
    const int cb  = blockIdx.y;           // 0..3, 128 cols each
    const int c4  = (tid & 31) * 4;       // col offset within 128
    const int rg  = tid >> 5;             // 0..7 -> rows rg*2, rg*2+1

    // stage A tile (16 x 128), clamp rows
#pragma unroll
    for (int l = 0; l < 2; l++) {
        int idx = tid + l * 256;
        int row = idx >> 5, cc = (idx & 31) * 4;
        int ra  = min(r0 + row, M - 1);
        *(float4*)&As[row * 128 + cc] = *(const float4*)(A + (size_t)ra * 128 + cc);
    }
    __syncthreads();

    const float* Bp = B + cb * 128 + c4;
    float acc[2][4] = {};
    for (int k = 0; k < 128; k += 4) {
        float4 a0 = *(const float4*)&As[(rg * 2 + 0) * 128 + k];
        float4 a1 = *(const float4*)&As[(rg * 2 + 1) * 128 + k];
        const float* pa0 = &a0.x;
        const float* pa1 = &a1.x;
#pragma unroll
        for (int u = 0; u < 4; u++) {
            float4 wv = *(const float4*)(Bp + (size_t)(k + u) * ldb);
            float v0 = pa0[u], v1 = pa1[u];
            acc[0][0] = fmaf(v0, wv.x, acc[0][0]);
            acc[0][1] = fmaf(v0, wv.y, acc[0][1]);
            acc[0][2] = fmaf(v0, wv.z, acc[0][2]);
            acc[0][3] = fmaf(v0, wv.w, acc[0][3]);
            acc[1][0] = fmaf(v1, wv.x, acc[1][0]);
            acc[1][1] = fmaf(v1, wv.y, acc[1][1]);
            acc[1][2] = fmaf(v1, wv.z, acc[1][2]);
            acc[1][3] = fmaf(v1, wv.w, acc[1][3]);
        }
    }
#pragma unroll
    for (int r = 0; r < 2; r++) {
        int row = r0 + rg * 2 + r;
        if (row < M) {
            float4 o = {acc[r][0], acc[r][1], acc[r][2], acc[r][3]};
            *(float4*)(C + (size_t)row * ldc + cb * 128 + c4) = o;
        }
    }
}

// Cvec[j] = sum_k oB1[k] * W2p[k][j] + B2p[j], j in [0,512)
__global__ __launch_bounds__(256) void k_cvec(const float* __restrict__ oB1,
                                              const float* __restrict__ W2p,
                                              const float* __restrict__ B2p,
                                              float* __restrict__ Cvec) {
    int j = blockIdx.x * 256 + threadIdx.x;
    if (j >= 512) return;
    float s = B2p[j];
    for (int k = 0; k < 128; k++) s = fmaf(oB1[k], W2p[k * 512 + j], s);
    Cvec[j] = s;
}

// out[t][j] = hshrink(PP[a][j] + QQ[b][j] + Cvec[j]); PPQQ is (1000 x 1024):
// PP in cols [0,512), QQ in cols [512,1024). 2 tpl rows per block.
__global__ __launch_bounds__(256) void k_final(const int* __restrict__ tpl,
                                               const float* __restrict__ PPQQ,
                                               const float* __restrict__ Cvec,
                                               float* __restrict__ out, int T, int S) {
    int t = blockIdx.x * 2 + (threadIdx.x >> 7);
    int i = threadIdx.x & 127;
    int nf4 = S >> 2;  // 125 for S=500
    if (t >= T || i >= nf4) return;
    int a = tpl[2 * t];
    int b = tpl[2 * t + 1];
    const float4* P = (const float4*)(PPQQ + (size_t)a * 1024) + i;
    const float4* Q = (const float4*)(PPQQ + (size_t)b * 1024 + 512) + i;
    float4 p = *P, q = *Q;
    float4 c = ((const float4*)Cvec)[i];
    float o0 = hshrink(p.x + q.x + c.x);
    float o1 = hshrink(p.y + q.y + c.y);
    float o2 = hshrink(p.z + q.z + c.z);
    float o3 = hshrink(p.w + q.w + c.w);
    float* po = out + (size_t)t * S + i * 4;
    // nontemporal: keep the 4 MB PPQQ working set resident in L2
    __builtin_nontemporal_store(o0, po + 0);
    __builtin_nontemporal_store(o1, po + 1);
    __builtin_nontemporal_store(o2, po + 2);
    __builtin_nontemporal_store(o3, po + 3);
}

extern "C" void kernel_launch(void* const* d_in, const int* in_sizes, int n_in,
                              void* d_out, int out_size, void* d_ws, size_t ws_size,
                              hipStream_t stream) {
    const float* dF   = (const float*)d_in[0];
    const int*   ei   = (const int*)d_in[1];
    const int*   tpl  = (const int*)d_in[2];
    const int*   sSes = (const int*)d_in[3];
    const float* W1   = (const float*)d_in[4];
    const float* b1   = (const float*)d_in[5];
    const float* W2   = (const float*)d_in[6];
    const float* b2   = (const float*)d_in[7];
    const float* pE   = (const float*)d_in[8];
    const float* sWl  = (const float*)d_in[9];
    const float* sBl  = (const float*)d_in[10];
    const float* sWr  = (const float*)d_in[11];
    const float* oW1  = (const float*)d_in[12];
    const float* oB1  = (const float*)d_in[13];
    const float* oW2  = (const float*)d_in[14];
    const float* oB2  = (const float*)d_in[15];

    const int D    = 128;
    const int F    = in_sizes[4] / D;   // 2048
    const int nD   = in_sizes[0] / F;   // 1000
    const int E    = in_sizes[1] / 2;   // 640000
    const int T    = in_sizes[2] / 2;   // 150000
    const int S    = in_sizes[3];       // 500
    const int nPro = in_sizes[8] / D;   // 20000
    const int nSe  = in_sizes[15];      // 964

    float* ws   = (float*)d_ws;
    float* xF   = ws;                               // (nD+nPro)*128
    float* h1   = xF + (size_t)(nD + nPro) * D;     // nD*128
    float* agg  = h1 + (size_t)nD * D;              // nD*128
    float* cnt  = agg + (size_t)nD * D;             // nD (padded to 1024)
    float* fX   = cnt + 1024;                       // nD*128
    float* W2p  = fX + (size_t)nD * D;              // 128*512
    float* B2p  = W2p + 128 * 512;                  // 512
    float* M2   = B2p + 512;                        // 256*512
    float* Cvec = M2 + 256 * 512;                   // 512
    float* PPQQ = Cvec + 512;                       // nD*1024

    // MLP: h1 = relu(dF@W1+b1); xF[:nD] = relu(h1@W2+b2)
    k_mlp<<<(nD + 7) / 8, 256, 0, stream>>>(dF, W1, b1, h1, nD, F);
    k_mlp<<<(nD + 7) / 8, 256, 0, stream>>>(h1, W2, b2, xF, nD, D);
    // xF[nD:] = proteinEmb
    hipMemcpyAsync(xF + (size_t)nD * D, pE, (size_t)nPro * D * sizeof(float),
                   hipMemcpyDeviceToDevice, stream);
    // zero agg + cnt
    hipMemsetAsync(agg, 0, ((size_t)nD * D + 1024) * sizeof(float), stream);
    // edge scatter (only dst < nD matters downstream)
    k_edge<<<(E * 4 + 255) / 256, 256, 0, stream>>>(ei, xF, agg, cnt, E, nD);
    // SAGE rows 0..nD-1 -> fX
    k_sage<<<(nD + 7) / 8, 256, 0, stream>>>(agg, cnt, xF, sWl, sBl, sWr, fX, nD);
    // gather sampled outW2 columns (padded to 512)
    k_w2g<<<(128 * 512 + 512 + 255) / 256, 256, 0, stream>>>(oW2, oB2, sSes, W2p, B2p,
                                                             nSe, S);
    // M2 = outW1 (256x128) @ W2p (128x512)
    {
        dim3 g((256 + 15) / 16, 4);
        k_g16<<<g, 256, 0, stream>>>(oW1, W2p, M2, 256, 512, 512);
    }
    // Cvec = oB1 @ W2p + B2p
    k_cvec<<<2, 256, 0, stream>>>(oB1, W2p, B2p, Cvec);
    // PP = fX @ M2[0:128]   -> PPQQ cols [0,512)
    // QQ = fX @ M2[128:256] -> PPQQ cols [512,1024)
    {
        dim3 g((nD + 15) / 16, 4);
        k_g16<<<g, 256, 0, stream>>>(fX, M2, PPQQ, nD, 512, 1024);
        k_g16<<<g, 256, 0, stream>>>(fX, M2 + (size_t)128 * 512, PPQQ + 512, nD, 512,
                                     1024);
    }
    // final streaming epilogue
    k_final<<<(T + 1) / 2, 256, 0, stream>>>(tpl, PPQQ, Cvec, (float*)d_out, T, S);
}